// Round 6
// baseline (58.362 us; speedup 1.0000x reference)
//
#include <hip/hip_runtime.h>
#include <math.h>

// DIAGNOSTIC ROUND: identical algorithm to R5, body wrapped in REPEAT=6 loop
// so the dispatch out-durations the harness poison-fills and shows up in the
// rocprof top-5 with real counters. Each iteration computes and stores
// identical values -> deterministic, passes re-validation.
//
// SourceModuleHnNSF: harmonic source + noise + uv from f0 contour.
// rev[b, f*upp+j] = (P[b,f]*upp + f0[b,f]*(j+1)) / SR,  P = excl frame prefix
// Chebyshev recurrence for harmonics, Pade tanh with v_rcp.

#define NHARM 9  // HARMONIC_NUM + 1

typedef float f32x4 __attribute__((ext_vector_type(4)));

// ---------------- fused kernel (UPP compile-time) ----------------
template <int UPP, int REPEAT>
__global__ __launch_bounds__(256) void hnnsf_fused(
    const float* __restrict__ f0, const float* __restrict__ W,
    const float* __restrict__ bptr, const float* __restrict__ noise,
    float* __restrict__ out, int frames, int S, int N,
    double upp_over_sr, float inv_sr) {
  constexpr int SPT = 4;
  constexpr int BLK = 256;
  constexpr int CHUNK = SPT * BLK;  // 1024
  const int b = blockIdx.y;
  const int t0_blk = blockIdx.x * CHUNK;  // sample offset within row
  const int tid = threadIdx.x;

  const float* f0row = f0 + b * frames;
  const int i0 = t0_blk + tid * SPT;  // row-local sample index
  const bool active = i0 < S;
  const int g0 = b * S + i0;
  const float nscale = (float)(0.1 / 3.0);

  const int f_start = t0_blk / UPP;
  const int t_last = min(t0_blk + CHUNK - 1, S - 1);
  const int nf = t_last / UPP - f_start + 1;  // <= 5 for UPP=300

  __shared__ double s_part[4];
  __shared__ float2 s_tab[8];  // {bfrac, f0/SR} per frame
  __shared__ float s_f0[8];
  const int wid = tid >> 6, lane = tid & 63;

  for (int rep = 0; rep < REPEAT; ++rep) {
    // ---- noise plane first: independent of f0, overlaps the prologue ----
    if (active) {
      const f32x4 nz = *reinterpret_cast<const f32x4*>(noise + g0);
      *reinterpret_cast<f32x4*>(out + N + g0) = nz * nscale;
    }

    // ---- block-redundant f64 prefix of f0row[0..f_start) ----
    double local = 0.0;
    for (int t = tid; t < f_start; t += BLK) local += (double)f0row[t];
#pragma unroll
    for (int off = 32; off >= 1; off >>= 1)
      local += __shfl_down(local, off, 64);

    if (lane == 0) s_part[wid] = local;
    if (tid < nf) s_f0[tid] = f0row[f_start + tid];
    __syncthreads();
    if (tid < nf) {
      double P = s_part[0] + s_part[1] + s_part[2] + s_part[3];
      for (int r = 0; r < tid; ++r) P += (double)s_f0[r];
      double rv = P * upp_over_sr;  // P*upp/SR in f64
      s_tab[tid] = make_float2((float)(rv - floor(rv)), s_f0[tid] * inv_sr);
    }
    __syncthreads();

    if (active) {
      float w[NHARM];
#pragma unroll
      for (int h = 0; h < NHARM; ++h) w[h] = W[h] * 0.1f;  // fold SINE_AMP
      const float bias = bptr[0];

      float harr[SPT], uvr[SPT];
#pragma unroll
      for (int k = 0; k < SPT; ++k) {
        const int t = i0 + k;
        const int f = t / UPP;  // magic-mul
        const int j = t - f * UPP;
        const float2 fr = s_tab[f - f_start];  // LDS broadcast
        const float uv = (fr.y > 0.0f) ? 1.0f : 0.0f;
        const float rf =
            __builtin_amdgcn_fractf(fmaf(fr.y, (float)(j + 1), fr.x));

        // Chebyshev: sin(2*pi*h*rf) from sin/cos of base angle.
        const float s1 = __builtin_amdgcn_sinf(rf);
        const float c2 = 2.0f * __builtin_amdgcn_cosf(rf);
        float sm2 = 0.0f, sm1 = s1;
        float acc = w[0] * s1;
#pragma unroll
        for (int h = 2; h <= NHARM; ++h) {
          const float sh = fmaf(c2, sm1, -sm2);
          acc = fmaf(w[h - 1], sh, acc);
          sm2 = sm1;
          sm1 = sh;
        }
        const float z = fmaf(uv, acc, bias);
        const float z2 = z * z;
        harr[k] =
            z * (27.0f + z2) * __builtin_amdgcn_rcpf(fmaf(9.0f, z2, 27.0f));
        uvr[k] = uv;
      }

      *reinterpret_cast<f32x4*>(out + g0) =
          (f32x4){harr[0], harr[1], harr[2], harr[3]};
      *reinterpret_cast<f32x4*>(out + 2 * N + g0) =
          (f32x4){uvr[0], uvr[1], uvr[2], uvr[3]};
    }
  }
}

// ---------------- generic fallback (upp != 300): two-kernel ----------------
__global__ __launch_bounds__(64) void f0_scan_kernel(
    const float* __restrict__ f0, float2* __restrict__ tab, int frames,
    double upp_over_sr, float inv_sr) {
  const int b = blockIdx.x;
  const int lane = threadIdx.x;
  const int per = (frames + 63) / 64;

  double vals[16];
  double local = 0.0;
#pragma unroll
  for (int i = 0; i < 16; ++i) {
    if (i < per) {
      int f = lane * per + i;
      double v = (f < frames) ? (double)f0[b * frames + f] : 0.0;
      vals[i] = local;
      local += v;
    }
  }
  double incl = local;
#pragma unroll
  for (int off = 1; off < 64; off <<= 1) {
    double v = __shfl_up(incl, off, 64);
    if (lane >= off) incl += v;
  }
  const double excl = incl - local;
#pragma unroll
  for (int i = 0; i < 16; ++i) {
    if (i < per) {
      int f = lane * per + i;
      if (f < frames) {
        double rev = (excl + vals[i]) * upp_over_sr;
        tab[b * frames + f] =
            make_float2((float)(rev - floor(rev)), f0[b * frames + f] * inv_sr);
      }
    }
  }
}

__global__ __launch_bounds__(256) void hnnsf_generic(
    const float* __restrict__ W, const float* __restrict__ bptr,
    const float* __restrict__ noise, const float2* __restrict__ tab,
    float* __restrict__ out, int frames, int upp, int S, int N) {
  const int tid = blockIdx.x * blockDim.x + threadIdx.x;
  const int i0 = tid * 4;
  if (i0 >= N) return;
  const int b = i0 / S;
  const int t0 = i0 - b * S;

  float w[NHARM];
#pragma unroll
  for (int h = 0; h < NHARM; ++h) w[h] = W[h] * 0.1f;
  const float bias = bptr[0];
  const float nscale = (float)(0.1 / 3.0);
  const f32x4 nz = *reinterpret_cast<const f32x4*>(noise + i0);

  float harr[4], uvr[4];
#pragma unroll
  for (int k = 0; k < 4; ++k) {
    const int t = t0 + k;
    const int f = t / upp;
    const int j = t - f * upp;
    const float2 fr = tab[b * frames + f];
    const float uv = (fr.y > 0.0f) ? 1.0f : 0.0f;
    const float rf = __builtin_amdgcn_fractf(fmaf(fr.y, (float)(j + 1), fr.x));
    float acc = 0.0f;
#pragma unroll
    for (int h = 1; h <= NHARM; ++h) {
      const float x = __builtin_amdgcn_fractf(rf * (float)h);
      acc = fmaf(w[h - 1], __builtin_amdgcn_sinf(x), acc);
    }
    const float z = fmaf(uv, acc, bias);
    const float z2 = z * z;
    harr[k] = z * (27.0f + z2) * __builtin_amdgcn_rcpf(fmaf(9.0f, z2, 27.0f));
    uvr[k] = uv;
  }
  *reinterpret_cast<f32x4*>(out + i0) = (f32x4){harr[0], harr[1], harr[2], harr[3]};
  *reinterpret_cast<f32x4*>(out + N + i0) = nz * nscale;
  *reinterpret_cast<f32x4*>(out + 2 * N + i0) = (f32x4){uvr[0], uvr[1], uvr[2], uvr[3]};
}

extern "C" void kernel_launch(void* const* d_in, const int* in_sizes, int n_in,
                              void* d_out, int out_size, void* d_ws,
                              size_t ws_size, hipStream_t stream) {
  const float* f0 = (const float*)d_in[0];
  const float* W = (const float*)d_in[1];
  const float* bptr = (const float*)d_in[2];
  const float* noise = (const float*)d_in[3];
  const int BF = in_sizes[0];   // B * frames = 16000
  const int NS = in_sizes[3];   // B * S = 4,800,000
  const int upp = NS / BF;      // 300
  const int B = 16;             // from setup_inputs
  const int frames = BF / B;    // 1000
  const int S = frames * upp;   // 300,000
  const int N = NS;
  const double upp_over_sr = (double)upp / 24000.0;
  const float inv_sr = (float)(1.0 / 24000.0);
  float* out = (float*)d_out;

  if (upp == 300) {
    const int CHUNK = 1024;
    dim3 grid((S + CHUNK - 1) / CHUNK, B);  // (293, 16)
    // REPEAT=6: diagnostic only — makes this dispatch the top-duration one
    // so rocprof top-5 finally includes it.
    hnnsf_fused<300, 6><<<grid, 256, 0, stream>>>(f0, W, bptr, noise, out,
                                                  frames, S, N, upp_over_sr,
                                                  inv_sr);
  } else {
    float2* tab = (float2*)d_ws;
    f0_scan_kernel<<<B, 64, 0, stream>>>(f0, tab, frames, upp_over_sr, inv_sr);
    const int grid = (N / 4 + 255) / 256;
    hnnsf_generic<<<grid, 256, 0, stream>>>(W, bptr, noise, tab, out, frames,
                                            upp, S, N);
  }
}

// Round 7
// 21.954 us; speedup vs baseline: 2.6584x; 2.6584x over previous
//
#include <hip/hip_runtime.h>
#include <math.h>

// SourceModuleHnNSF: harmonic source + noise + uv from f0 contour.
// Outputs (concat flat f32): har [B,S], noise_out [B,S], uv [B,S]; S=F*upp.
//
// R6 diagnostic found: steady-state pass = 7.5 us (L2-hot), one-shot = 20.7 us.
// Fixed cost is first-pass L2 cold misses + write-allocate on the 57.6 MB of
// streaming output stores. This round: NONTEMPORAL stores for all three output
// planes (+ nt load for noise) to bypass L2 write-allocate. Algorithm is
// unchanged from R5 (Chebyshev harmonics, Pade tanh, block-redundant f64
// frame prefix, noise-plane-first ordering).

#define NHARM 9  // HARMONIC_NUM + 1

typedef float f32x4 __attribute__((ext_vector_type(4)));

// ---------------- fused kernel (UPP compile-time) ----------------
template <int UPP>
__global__ __launch_bounds__(256) void hnnsf_fused(
    const float* __restrict__ f0, const float* __restrict__ W,
    const float* __restrict__ bptr, const float* __restrict__ noise,
    float* __restrict__ out, int frames, int S, int N,
    double upp_over_sr, float inv_sr) {
  constexpr int SPT = 4;
  constexpr int BLK = 256;
  constexpr int CHUNK = SPT * BLK;  // 1024
  const int b = blockIdx.y;
  const int t0_blk = blockIdx.x * CHUNK;  // sample offset within row
  const int tid = threadIdx.x;

  const float* f0row = f0 + b * frames;
  const int i0 = t0_blk + tid * SPT;  // row-local sample index
  const bool active = i0 < S;         // S % 4 == 0 -> whole-thread guard
  const int g0 = b * S + i0;
  const float nscale = (float)(0.1 / 3.0);

  // ---- noise plane first: independent of f0, overlaps the prologue ----
  if (active) {
    const f32x4 nz =
        __builtin_nontemporal_load(reinterpret_cast<const f32x4*>(noise + g0));
    __builtin_nontemporal_store(nz * nscale,
                                reinterpret_cast<f32x4*>(out + N + g0));
  }

  const int f_start = t0_blk / UPP;
  const int t_last = min(t0_blk + CHUNK - 1, S - 1);
  const int nf = t_last / UPP - f_start + 1;  // <= 5 for UPP=300

  // ---- block-redundant f64 prefix of f0row[0..f_start) ----
  double local = 0.0;
  for (int t = tid; t < f_start; t += BLK) local += (double)f0row[t];
#pragma unroll
  for (int off = 32; off >= 1; off >>= 1) local += __shfl_down(local, off, 64);

  __shared__ double s_part[4];
  __shared__ float2 s_tab[8];  // {bfrac, f0/SR} per frame
  __shared__ float s_f0[8];
  const int wid = tid >> 6, lane = tid & 63;
  if (lane == 0) s_part[wid] = local;
  if (tid < nf) s_f0[tid] = f0row[f_start + tid];
  __syncthreads();
  if (tid < nf) {
    double P = s_part[0] + s_part[1] + s_part[2] + s_part[3];
    for (int r = 0; r < tid; ++r) P += (double)s_f0[r];
    double rv = P * upp_over_sr;  // P*upp/SR in f64
    s_tab[tid] = make_float2((float)(rv - floor(rv)), s_f0[tid] * inv_sr);
  }
  __syncthreads();
  if (!active) return;

  float w[NHARM];
#pragma unroll
  for (int h = 0; h < NHARM; ++h) w[h] = W[h] * 0.1f;  // fold SINE_AMP
  const float bias = bptr[0];

  float harr[SPT], uvr[SPT];
#pragma unroll
  for (int k = 0; k < SPT; ++k) {
    const int t = i0 + k;
    const int f = t / UPP;  // magic-mul
    const int j = t - f * UPP;
    const float2 fr = s_tab[f - f_start];  // LDS broadcast
    const float uv = (fr.y > 0.0f) ? 1.0f : 0.0f;
    const float rf = __builtin_amdgcn_fractf(fmaf(fr.y, (float)(j + 1), fr.x));

    // Chebyshev: sin(2*pi*h*rf) via recurrence from sin/cos of base angle.
    const float s1 = __builtin_amdgcn_sinf(rf);  // sin(2*pi*rf)
    const float c2 = 2.0f * __builtin_amdgcn_cosf(rf);
    float sm2 = 0.0f, sm1 = s1;
    float acc = w[0] * s1;
#pragma unroll
    for (int h = 2; h <= NHARM; ++h) {
      const float sh = fmaf(c2, sm1, -sm2);
      acc = fmaf(w[h - 1], sh, acc);
      sm2 = sm1;
      sm1 = sh;
    }
    const float z = fmaf(uv, acc, bias);
    // Pade tanh with fast rcp: z*(27+z^2)/(27+9z^2), |z|<~0.6 -> err <1e-5
    const float z2 = z * z;
    harr[k] = z * (27.0f + z2) * __builtin_amdgcn_rcpf(fmaf(9.0f, z2, 27.0f));
    uvr[k] = uv;
  }

  __builtin_nontemporal_store((f32x4){harr[0], harr[1], harr[2], harr[3]},
                              reinterpret_cast<f32x4*>(out + g0));
  __builtin_nontemporal_store((f32x4){uvr[0], uvr[1], uvr[2], uvr[3]},
                              reinterpret_cast<f32x4*>(out + 2 * N + g0));
}

// ---------------- generic fallback (upp != 300): two-kernel ----------------
__global__ __launch_bounds__(64) void f0_scan_kernel(
    const float* __restrict__ f0, float2* __restrict__ tab, int frames,
    double upp_over_sr, float inv_sr) {
  const int b = blockIdx.x;
  const int lane = threadIdx.x;
  const int per = (frames + 63) / 64;

  double vals[16];
  double local = 0.0;
#pragma unroll
  for (int i = 0; i < 16; ++i) {
    if (i < per) {
      int f = lane * per + i;
      double v = (f < frames) ? (double)f0[b * frames + f] : 0.0;
      vals[i] = local;
      local += v;
    }
  }
  double incl = local;
#pragma unroll
  for (int off = 1; off < 64; off <<= 1) {
    double v = __shfl_up(incl, off, 64);
    if (lane >= off) incl += v;
  }
  const double excl = incl - local;
#pragma unroll
  for (int i = 0; i < 16; ++i) {
    if (i < per) {
      int f = lane * per + i;
      if (f < frames) {
        double rev = (excl + vals[i]) * upp_over_sr;
        tab[b * frames + f] =
            make_float2((float)(rev - floor(rev)), f0[b * frames + f] * inv_sr);
      }
    }
  }
}

__global__ __launch_bounds__(256) void hnnsf_generic(
    const float* __restrict__ W, const float* __restrict__ bptr,
    const float* __restrict__ noise, const float2* __restrict__ tab,
    float* __restrict__ out, int frames, int upp, int S, int N) {
  const int tid = blockIdx.x * blockDim.x + threadIdx.x;
  const int i0 = tid * 4;
  if (i0 >= N) return;
  const int b = i0 / S;
  const int t0 = i0 - b * S;

  float w[NHARM];
#pragma unroll
  for (int h = 0; h < NHARM; ++h) w[h] = W[h] * 0.1f;
  const float bias = bptr[0];
  const float nscale = (float)(0.1 / 3.0);
  const f32x4 nz = *reinterpret_cast<const f32x4*>(noise + i0);

  float harr[4], uvr[4];
#pragma unroll
  for (int k = 0; k < 4; ++k) {
    const int t = t0 + k;
    const int f = t / upp;
    const int j = t - f * upp;
    const float2 fr = tab[b * frames + f];
    const float uv = (fr.y > 0.0f) ? 1.0f : 0.0f;
    const float rf = __builtin_amdgcn_fractf(fmaf(fr.y, (float)(j + 1), fr.x));
    float acc = 0.0f;
#pragma unroll
    for (int h = 1; h <= NHARM; ++h) {
      const float x = __builtin_amdgcn_fractf(rf * (float)h);
      acc = fmaf(w[h - 1], __builtin_amdgcn_sinf(x), acc);
    }
    const float z = fmaf(uv, acc, bias);
    const float z2 = z * z;
    harr[k] = z * (27.0f + z2) * __builtin_amdgcn_rcpf(fmaf(9.0f, z2, 27.0f));
    uvr[k] = uv;
  }
  *reinterpret_cast<f32x4*>(out + i0) = (f32x4){harr[0], harr[1], harr[2], harr[3]};
  *reinterpret_cast<f32x4*>(out + N + i0) = nz * nscale;
  *reinterpret_cast<f32x4*>(out + 2 * N + i0) = (f32x4){uvr[0], uvr[1], uvr[2], uvr[3]};
}

extern "C" void kernel_launch(void* const* d_in, const int* in_sizes, int n_in,
                              void* d_out, int out_size, void* d_ws,
                              size_t ws_size, hipStream_t stream) {
  const float* f0 = (const float*)d_in[0];
  const float* W = (const float*)d_in[1];
  const float* bptr = (const float*)d_in[2];
  const float* noise = (const float*)d_in[3];
  const int BF = in_sizes[0];   // B * frames = 16000
  const int NS = in_sizes[3];   // B * S = 4,800,000
  const int upp = NS / BF;      // 300
  const int B = 16;             // from setup_inputs
  const int frames = BF / B;    // 1000
  const int S = frames * upp;   // 300,000
  const int N = NS;
  const double upp_over_sr = (double)upp / 24000.0;
  const float inv_sr = (float)(1.0 / 24000.0);
  float* out = (float*)d_out;

  if (upp == 300) {
    const int CHUNK = 1024;
    dim3 grid((S + CHUNK - 1) / CHUNK, B);  // (293, 16)
    hnnsf_fused<300><<<grid, 256, 0, stream>>>(f0, W, bptr, noise, out, frames,
                                               S, N, upp_over_sr, inv_sr);
  } else {
    float2* tab = (float2*)d_ws;
    f0_scan_kernel<<<B, 64, 0, stream>>>(f0, tab, frames, upp_over_sr, inv_sr);
    const int grid = (N / 4 + 255) / 256;
    hnnsf_generic<<<grid, 256, 0, stream>>>(W, bptr, noise, tab, out, frames,
                                            upp, S, N);
  }
}

// Round 8
// 18.233 us; speedup vs baseline: 3.2009x; 1.2041x over previous
//
#include <hip/hip_runtime.h>
#include <math.h>

// SourceModuleHnNSF: harmonic source + noise + uv from f0 contour.
// Outputs (concat flat f32): har [B,S], noise_out [B,S], uv [B,S]; S=F*upp.
//
// R6/R7 evidence: steady-state pass 7.5 us, one-shot 20.7; nt stores neutral
// (write-allocate not the cost). Remaining suspect: per-block prologue latency
// repeated 4688x. This round: span-persistent blocks — each block owns 16
// frames (4800 samples), pays ONE prologue (block-redundant f64 prefix of
// f0row[0..f_start)), builds ONE 16-entry {bfrac, f0/SR} LDS table, then
// processes 5 chunked x 1024 samples with no barriers in the loop. Noise
// loads issued up-front (static unrolled indices); noise stores issued before
// the prologue so the write stream flows during the f64 reduce.
// Math unchanged: rf = fract(bfrac + f0n*(j+1)); Chebyshev recurrence from
// v_sin/v_cos of base angle; Pade tanh with v_rcp.

#define NHARM 9  // HARMONIC_NUM + 1

typedef float f32x4 __attribute__((ext_vector_type(4)));

// ---------------- span kernel (UPP, frames-per-block compile-time) ----------
template <int UPP, int FPB>
__global__ __launch_bounds__(256) void hnnsf_span(
    const float* __restrict__ f0, const float* __restrict__ W,
    const float* __restrict__ bptr, const float* __restrict__ noise,
    float* __restrict__ out, int frames, int S, int N,
    double upp_over_sr, float inv_sr) {
  constexpr int BLK = 256;
  constexpr int CHUNK = BLK * 4;                          // 1024 samples
  constexpr int MAXC = (FPB * UPP + CHUNK - 1) / CHUNK;   // 5 for 16x300
  const int b = blockIdx.y;
  const int f_start = blockIdx.x * FPB;
  const int nf = min(FPB, frames - f_start);              // 16 (8 in tail blk)
  const int t_begin = f_start * UPP;                      // row-local sample
  const int t_end = t_begin + nf * UPP;
  const int tid = threadIdx.x;
  const float* f0row = f0 + b * frames;
  const int rowbase = b * S;
  const float nscale = (float)(0.1 / 3.0);

  // ---- noise: prefetch + store all chunks up-front (static idx, rule #20) --
  f32x4 nz[MAXC];
  int tloc[MAXC];
  bool act[MAXC];
#pragma unroll
  for (int c = 0; c < MAXC; ++c) {
    tloc[c] = t_begin + c * CHUNK + tid * 4;
    act[c] = tloc[c] < t_end;
    if (act[c])
      nz[c] = *reinterpret_cast<const f32x4*>(noise + rowbase + tloc[c]);
  }
#pragma unroll
  for (int c = 0; c < MAXC; ++c)
    if (act[c])
      *reinterpret_cast<f32x4*>(out + N + rowbase + tloc[c]) = nz[c] * nscale;

  // ---- block-redundant f64 prefix of f0row[0..f_start) ----
  double local = 0.0;
  for (int t = tid; t < f_start; t += BLK) local += (double)f0row[t];
#pragma unroll
  for (int off = 32; off >= 1; off >>= 1) local += __shfl_down(local, off, 64);

  __shared__ double s_part[4];
  __shared__ float2 s_tab[FPB];  // {bfrac, f0/SR} per frame
  __shared__ float s_f0[FPB];
  const int wid = tid >> 6, lane = tid & 63;
  if (lane == 0) s_part[wid] = local;
  if (tid < nf) s_f0[tid] = f0row[f_start + tid];
  __syncthreads();
  if (tid < nf) {
    double P = s_part[0] + s_part[1] + s_part[2] + s_part[3];
    for (int r = 0; r < tid; ++r) P += (double)s_f0[r];
    double rv = P * upp_over_sr;  // P*upp/SR in f64
    s_tab[tid] = make_float2((float)(rv - floor(rv)), s_f0[tid] * inv_sr);
  }
  __syncthreads();  // table ready; no barriers needed after this

  float w[NHARM];
#pragma unroll
  for (int h = 0; h < NHARM; ++h) w[h] = W[h] * 0.1f;  // fold SINE_AMP
  const float bias = bptr[0];

  // ---- main loop: 5 chunks, barrier-free ----
#pragma unroll
  for (int c = 0; c < MAXC; ++c) {
    if (!act[c]) continue;
    const int tl = tloc[c] - t_begin;  // local sample in [0, FPB*UPP)
    float harr[4], uvr[4];
#pragma unroll
    for (int k = 0; k < 4; ++k) {
      const int f_l = (tl + k) / UPP;  // magic-mul
      const int j = (tl + k) - f_l * UPP;
      const float2 fr = s_tab[f_l];    // LDS broadcast
      const float uv = (fr.y > 0.0f) ? 1.0f : 0.0f;
      const float rf =
          __builtin_amdgcn_fractf(fmaf(fr.y, (float)(j + 1), fr.x));

      // Chebyshev: sin(2*pi*h*rf) from sin/cos of base angle.
      const float s1 = __builtin_amdgcn_sinf(rf);
      const float c2 = 2.0f * __builtin_amdgcn_cosf(rf);
      float sm2 = 0.0f, sm1 = s1;
      float acc = w[0] * s1;
#pragma unroll
      for (int h = 2; h <= NHARM; ++h) {
        const float sh = fmaf(c2, sm1, -sm2);
        acc = fmaf(w[h - 1], sh, acc);
        sm2 = sm1;
        sm1 = sh;
      }
      const float z = fmaf(uv, acc, bias);
      // Pade tanh: z*(27+z^2)/(27+9z^2), |z|<~0.6 -> err <1e-5
      const float z2 = z * z;
      harr[k] = z * (27.0f + z2) * __builtin_amdgcn_rcpf(fmaf(9.0f, z2, 27.0f));
      uvr[k] = uv;
    }
    *reinterpret_cast<f32x4*>(out + rowbase + tloc[c]) =
        (f32x4){harr[0], harr[1], harr[2], harr[3]};
    *reinterpret_cast<f32x4*>(out + 2 * N + rowbase + tloc[c]) =
        (f32x4){uvr[0], uvr[1], uvr[2], uvr[3]};
  }
}

// ---------------- generic fallback (upp != 300): two-kernel ----------------
__global__ __launch_bounds__(64) void f0_scan_kernel(
    const float* __restrict__ f0, float2* __restrict__ tab, int frames,
    double upp_over_sr, float inv_sr) {
  const int b = blockIdx.x;
  const int lane = threadIdx.x;
  const int per = (frames + 63) / 64;

  double vals[16];
  double local = 0.0;
#pragma unroll
  for (int i = 0; i < 16; ++i) {
    if (i < per) {
      int f = lane * per + i;
      double v = (f < frames) ? (double)f0[b * frames + f] : 0.0;
      vals[i] = local;
      local += v;
    }
  }
  double incl = local;
#pragma unroll
  for (int off = 1; off < 64; off <<= 1) {
    double v = __shfl_up(incl, off, 64);
    if (lane >= off) incl += v;
  }
  const double excl = incl - local;
#pragma unroll
  for (int i = 0; i < 16; ++i) {
    if (i < per) {
      int f = lane * per + i;
      if (f < frames) {
        double rev = (excl + vals[i]) * upp_over_sr;
        tab[b * frames + f] =
            make_float2((float)(rev - floor(rev)), f0[b * frames + f] * inv_sr);
      }
    }
  }
}

__global__ __launch_bounds__(256) void hnnsf_generic(
    const float* __restrict__ W, const float* __restrict__ bptr,
    const float* __restrict__ noise, const float2* __restrict__ tab,
    float* __restrict__ out, int frames, int upp, int S, int N) {
  const int tid = blockIdx.x * blockDim.x + threadIdx.x;
  const int i0 = tid * 4;
  if (i0 >= N) return;
  const int b = i0 / S;
  const int t0 = i0 - b * S;

  float w[NHARM];
#pragma unroll
  for (int h = 0; h < NHARM; ++h) w[h] = W[h] * 0.1f;
  const float bias = bptr[0];
  const float nscale = (float)(0.1 / 3.0);
  const f32x4 nz = *reinterpret_cast<const f32x4*>(noise + i0);

  float harr[4], uvr[4];
#pragma unroll
  for (int k = 0; k < 4; ++k) {
    const int t = t0 + k;
    const int f = t / upp;
    const int j = t - f * upp;
    const float2 fr = tab[b * frames + f];
    const float uv = (fr.y > 0.0f) ? 1.0f : 0.0f;
    const float rf = __builtin_amdgcn_fractf(fmaf(fr.y, (float)(j + 1), fr.x));
    float acc = 0.0f;
#pragma unroll
    for (int h = 1; h <= NHARM; ++h) {
      const float x = __builtin_amdgcn_fractf(rf * (float)h);
      acc = fmaf(w[h - 1], __builtin_amdgcn_sinf(x), acc);
    }
    const float z = fmaf(uv, acc, bias);
    const float z2 = z * z;
    harr[k] = z * (27.0f + z2) * __builtin_amdgcn_rcpf(fmaf(9.0f, z2, 27.0f));
    uvr[k] = uv;
  }
  *reinterpret_cast<f32x4*>(out + i0) = (f32x4){harr[0], harr[1], harr[2], harr[3]};
  *reinterpret_cast<f32x4*>(out + N + i0) = nz * nscale;
  *reinterpret_cast<f32x4*>(out + 2 * N + i0) = (f32x4){uvr[0], uvr[1], uvr[2], uvr[3]};
}

extern "C" void kernel_launch(void* const* d_in, const int* in_sizes, int n_in,
                              void* d_out, int out_size, void* d_ws,
                              size_t ws_size, hipStream_t stream) {
  const float* f0 = (const float*)d_in[0];
  const float* W = (const float*)d_in[1];
  const float* bptr = (const float*)d_in[2];
  const float* noise = (const float*)d_in[3];
  const int BF = in_sizes[0];   // B * frames = 16000
  const int NS = in_sizes[3];   // B * S = 4,800,000
  const int upp = NS / BF;      // 300
  const int B = 16;             // from setup_inputs
  const int frames = BF / B;    // 1000
  const int S = frames * upp;   // 300,000
  const int N = NS;
  const double upp_over_sr = (double)upp / 24000.0;
  const float inv_sr = (float)(1.0 / 24000.0);
  float* out = (float*)d_out;

  if (upp == 300) {
    constexpr int FPB = 16;  // frames per block -> 4800 samples/block
    dim3 grid((frames + FPB - 1) / FPB, B);  // (63, 16) = 1008 blocks
    hnnsf_span<300, FPB><<<grid, 256, 0, stream>>>(f0, W, bptr, noise, out,
                                                   frames, S, N, upp_over_sr,
                                                   inv_sr);
  } else {
    float2* tab = (float2*)d_ws;
    f0_scan_kernel<<<B, 64, 0, stream>>>(f0, tab, frames, upp_over_sr, inv_sr);
    const int grid = (N / 4 + 255) / 256;
    hnnsf_generic<<<grid, 256, 0, stream>>>(W, bptr, noise, tab, out, frames,
                                            upp, S, N);
  }
}